// Round 1
// baseline (233.684 us; speedup 1.0000x reference)
//
#include <hip/hip_runtime.h>

#define N 8192

typedef __attribute__((ext_vector_type(8))) short short8;
typedef __attribute__((ext_vector_type(4))) float f32x4;

__device__ __forceinline__ unsigned short f2bf(float f) {
    union { float f; unsigned int u; } v; v.f = f;
    unsigned int r = v.u + 0x7FFFu + ((v.u >> 16) & 1u);  // round-to-nearest-even
    return (unsigned short)(r >> 16);
}

// ---------------------------------------------------------------------------
// Aggregation: y_partial[split] = adj[rows, ksplit] @ h   (h given transposed bf16)
// MODE 0: load adj f32 (no writeback)   MODE 1: load f32 + write bf16 copy
// MODE 2: load bf16 copy
// Tile: BM=64 rows x full NC cols, BK=64 k-chunk. 256 threads = 4 waves,
// wave w owns rows [16w,16w+16), NC/16 col-tiles, mfma_f32_16x16x32_bf16.
// LDS tiles are row-major bf16 (stride 128B) with XOR swizzle byte^=((row&7)<<4).
// ---------------------------------------------------------------------------
template<int NC, int MODE>
__global__ __launch_bounds__(256) void agg_kernel(
    const float* __restrict__ adj,
    const unsigned short* __restrict__ adj_b_in,
    unsigned short* __restrict__ adj_b_out,
    const unsigned short* __restrict__ hT,   // [NC][N] bf16
    float* __restrict__ y,                   // [SPLITK][N][NC] f32 partials
    int klen)
{
    constexpr int BM = 64, BK = 64;
    constexpr int NCT = NC / 16;
    __shared__ unsigned short as_[BM * BK];  // adj tile, swizzled
    __shared__ unsigned short hs_[NC * BK];  // hT tile,  swizzled
    char* asb = (char*)as_;
    char* hsb = (char*)hs_;

    const int tid = threadIdx.x;
    const int w  = tid >> 6;
    const int l  = tid & 63;
    const int hi = l >> 4;
    const int lr = l & 15;
    const int row0 = blockIdx.x * BM;
    const int k00  = blockIdx.y * klen;

    f32x4 acc[NCT];
    #pragma unroll
    for (int i = 0; i < NCT; ++i) acc[i] = f32x4{0.f, 0.f, 0.f, 0.f};

    for (int kc = 0; kc < klen; kc += BK) {
        const int kb = k00 + kc;
        // ---- stage adj tile (64x64) ----
        if (MODE == 2) {
            #pragma unroll
            for (int it = 0; it < 2; ++it) {
                int idx = tid + it * 256;          // 0..511 = 64 rows x 8 groups
                int r = idx >> 3, kq = idx & 7;    // 8 bf16 per group (16B)
                short8 v = *reinterpret_cast<const short8*>(
                    adj_b_in + (size_t)(row0 + r) * N + kb + 8 * kq);
                *reinterpret_cast<short8*>(
                    asb + r * 128 + ((16 * kq) ^ ((r & 7) << 4))) = v;
            }
        } else {
            #pragma unroll
            for (int it = 0; it < 4; ++it) {
                int idx = tid + it * 256;          // 0..1023 = 64 rows x 16 groups
                int r = idx >> 4, kq = idx & 15;   // float4 per group
                float4 v = *reinterpret_cast<const float4*>(
                    adj + (size_t)(row0 + r) * N + kb + 4 * kq);
                ushort4 u;
                u.x = f2bf(v.x); u.y = f2bf(v.y); u.z = f2bf(v.z); u.w = f2bf(v.w);
                *reinterpret_cast<ushort4*>(
                    asb + r * 128 + ((8 * kq) ^ ((r & 7) << 4))) = u;
                if (MODE == 1)
                    *reinterpret_cast<ushort4*>(
                        adj_b_out + (size_t)(row0 + r) * N + kb + 4 * kq) = u;
            }
        }
        // ---- stage hT tile (NC x 64) ----
        {
            constexpr int NU8 = NC * 8;            // 16B groups
            #pragma unroll
            for (int idx0 = 0; idx0 < NU8; idx0 += 256) {
                int idx = idx0 + tid;
                if (NU8 >= 256 || idx < NU8) {
                    int c = idx >> 3, kq = idx & 7;
                    short8 v = *reinterpret_cast<const short8*>(
                        hT + (size_t)c * N + kb + 8 * kq);
                    *reinterpret_cast<short8*>(
                        hsb + c * 128 + ((16 * kq) ^ ((c & 7) << 4))) = v;
                }
            }
        }
        __syncthreads();
        // ---- MFMA: 2 k-steps of 32 ----
        #pragma unroll
        for (int kk = 0; kk < BK; kk += 32) {
            const int arow = 16 * w + lr;
            short8 a = *reinterpret_cast<const short8*>(
                asb + arow * 128 + ((2 * kk + 16 * hi) ^ ((arow & 7) << 4)));
            #pragma unroll
            for (int ct = 0; ct < NCT; ++ct) {
                const int bcol = 16 * ct + lr;
                short8 b = *reinterpret_cast<const short8*>(
                    hsb + bcol * 128 + ((2 * kk + 16 * hi) ^ ((bcol & 7) << 4)));
                acc[ct] = __builtin_amdgcn_mfma_f32_16x16x32_bf16(a, b, acc[ct], 0, 0, 0);
            }
        }
        __syncthreads();
    }
    // ---- write partials: D layout col=lane&15, row=4*(lane>>4)+reg ----
    float* yp = y + (size_t)blockIdx.y * N * NC;
    #pragma unroll
    for (int ct = 0; ct < NCT; ++ct) {
        #pragma unroll
        for (int r = 0; r < 4; ++r) {
            yp[(size_t)(row0 + 16 * w + 4 * hi + r) * NC + 16 * ct + lr] = acc[ct][r];
        }
    }
}

// ---------------------------------------------------------------------------
// lin0: hT = bf16((x @ W0 + b0)^T)    x:[N,128] f32, W0:[128,16], hT:[16][N]
// 64 rows/block, wave w -> cols {w, w+4, w+8, w+12}, lane = row.
// ---------------------------------------------------------------------------
__global__ __launch_bounds__(256) void lin0_kernel(
    const float* __restrict__ x, const float* __restrict__ W,
    const float* __restrict__ b, unsigned short* __restrict__ hT)
{
    __shared__ float xs[64][129];
    const int tid = threadIdx.x;
    const int row0 = blockIdx.x * 64;
    #pragma unroll
    for (int it = 0; it < 8; ++it) {
        int idx = tid + it * 256;            // 0..2047 = 64 rows x 32 float4
        int r = idx >> 5, q = idx & 31;
        float4 v = *reinterpret_cast<const float4*>(x + (size_t)(row0 + r) * 128 + 4 * q);
        xs[r][4 * q + 0] = v.x; xs[r][4 * q + 1] = v.y;
        xs[r][4 * q + 2] = v.z; xs[r][4 * q + 3] = v.w;
    }
    __syncthreads();
    const int w = tid >> 6, l = tid & 63;
    float acc[4] = {b[w], b[w + 4], b[w + 8], b[w + 12]};
    for (int k = 0; k < 128; ++k) {
        float xv = xs[l][k];
        #pragma unroll
        for (int cc = 0; cc < 4; ++cc) acc[cc] += xv * W[k * 16 + w + 4 * cc];
    }
    #pragma unroll
    for (int cc = 0; cc < 4; ++cc)
        hT[(size_t)(w + 4 * cc) * N + row0 + l] = f2bf(acc[cc]);
}

// ---------------------------------------------------------------------------
// mid linear: hT = bf16((relu(sum_s y_s) @ W + b)^T)
// ---------------------------------------------------------------------------
template<int NIN, int NOUT, int S>
__global__ __launch_bounds__(256) void mid_linear_kernel(
    const float* __restrict__ y,     // [S][N][NIN]
    const float* __restrict__ W,     // [NIN][NOUT]
    const float* __restrict__ b,
    unsigned short* __restrict__ hT) // [NOUT][N]
{
    __shared__ float xs[64][NIN + 1];
    const int tid = threadIdx.x;
    const int row0 = blockIdx.x * 64;
    constexpr int NF4 = 64 * NIN / 4;
    #pragma unroll
    for (int idx0 = 0; idx0 < NF4; idx0 += 256) {
        int idx = idx0 + tid;
        int r = idx / (NIN / 4), q = idx % (NIN / 4);
        size_t off = (size_t)(row0 + r) * NIN + 4 * q;
        float4 v = *reinterpret_cast<const float4*>(y + off);
        #pragma unroll
        for (int s = 1; s < S; ++s) {
            float4 t = *reinterpret_cast<const float4*>(y + (size_t)s * N * NIN + off);
            v.x += t.x; v.y += t.y; v.z += t.z; v.w += t.w;
        }
        xs[r][4 * q + 0] = fmaxf(v.x, 0.f);
        xs[r][4 * q + 1] = fmaxf(v.y, 0.f);
        xs[r][4 * q + 2] = fmaxf(v.z, 0.f);
        xs[r][4 * q + 3] = fmaxf(v.w, 0.f);
    }
    __syncthreads();
    const int w = tid >> 6, l = tid & 63;
    constexpr int CC = NOUT / 4;
    float acc[CC];
    #pragma unroll
    for (int cc = 0; cc < CC; ++cc) acc[cc] = b[w + 4 * cc];
    for (int k = 0; k < NIN; ++k) {
        float xv = xs[l][k];
        #pragma unroll
        for (int cc = 0; cc < CC; ++cc) acc[cc] += xv * W[k * NOUT + w + 4 * cc];
    }
    #pragma unroll
    for (int cc = 0; cc < CC; ++cc)
        hT[(size_t)(w + 4 * cc) * N + row0 + l] = f2bf(acc[cc]);
}

// ---------------------------------------------------------------------------
// head: out = relu(relu(sum_s y_s) @ Wo0 + bo0) @ Wo1 + bo1
// 4 rows/block, one wave per row.
// ---------------------------------------------------------------------------
template<int S>
__global__ __launch_bounds__(256) void head_kernel(
    const float* __restrict__ y,   // [S][N][64]
    const float* __restrict__ Wo0, const float* __restrict__ bo0,
    const float* __restrict__ Wo1, const float* __restrict__ bo1,
    float* __restrict__ out)
{
    __shared__ float xr[4][64];
    __shared__ float hid[4][32];
    const int tid = threadIdx.x;
    const int row0 = blockIdx.x * 4;
    {
        int r = tid >> 6, k = tid & 63;
        size_t off = (size_t)(row0 + r) * 64 + k;
        float v = y[off];
        #pragma unroll
        for (int s = 1; s < S; ++s) v += y[(size_t)s * N * 64 + off];
        xr[r][k] = fmaxf(v, 0.f);
    }
    __syncthreads();
    const int w = tid >> 6, l = tid & 63;
    if (l < 32) {
        float acc = bo0[l];
        #pragma unroll
        for (int k = 0; k < 64; ++k) acc += xr[w][k] * Wo0[k * 32 + l];
        hid[w][l] = fmaxf(acc, 0.f);
    }
    __syncthreads();
    if (l < 10) {
        float acc = bo1[l];
        #pragma unroll
        for (int k = 0; k < 32; ++k) acc += hid[w][k] * Wo1[k * 10 + l];
        out[(size_t)(row0 + w) * 10 + l] = acc;
    }
}

extern "C" void kernel_launch(void* const* d_in, const int* in_sizes, int n_in,
                              void* d_out, int out_size, void* d_ws, size_t ws_size,
                              hipStream_t stream) {
    const float* x   = (const float*)d_in[0];
    const float* adj = (const float*)d_in[1];
    const float* W0  = (const float*)d_in[2];
    const float* b0  = (const float*)d_in[3];
    const float* W1  = (const float*)d_in[4];
    const float* b1  = (const float*)d_in[5];
    const float* W2  = (const float*)d_in[6];
    const float* b2  = (const float*)d_in[7];
    const float* Wo0 = (const float*)d_in[8];
    const float* bo0 = (const float*)d_in[9];
    const float* Wo1 = (const float*)d_in[10];
    const float* bo1 = (const float*)d_in[11];
    float* out = (float*)d_out;

    char* ws = (char*)d_ws;
    constexpr int SPLITK = 4;
    float* y_part          = (float*)ws;                          // 4*8192*64*4 = 8 MiB
    unsigned short* hT     = (unsigned short*)(ws + (8u << 20));  // <= 1 MiB
    unsigned short* adj_b  = (unsigned short*)(ws + (16u << 20)); // 128 MiB
    const size_t NEED_FULL = ((size_t)16 << 20) + (size_t)N * N * 2;
    const bool cache = ws_size >= NEED_FULL;
    const int klen = N / SPLITK;

    lin0_kernel<<<128, 256, 0, stream>>>(x, W0, b0, hT);

    if (cache)
        agg_kernel<16, 1><<<dim3(128, SPLITK), 256, 0, stream>>>(adj, nullptr, adj_b, hT, y_part, klen);
    else
        agg_kernel<16, 0><<<dim3(128, SPLITK), 256, 0, stream>>>(adj, nullptr, nullptr, hT, y_part, klen);

    mid_linear_kernel<16, 32, SPLITK><<<128, 256, 0, stream>>>(y_part, W1, b1, hT);

    if (cache)
        agg_kernel<32, 2><<<dim3(128, SPLITK), 256, 0, stream>>>(adj, adj_b, nullptr, hT, y_part, klen);
    else
        agg_kernel<32, 0><<<dim3(128, SPLITK), 256, 0, stream>>>(adj, nullptr, nullptr, hT, y_part, klen);

    mid_linear_kernel<32, 64, SPLITK><<<128, 256, 0, stream>>>(y_part, W2, b2, hT);

    if (cache)
        agg_kernel<64, 2><<<dim3(128, SPLITK), 256, 0, stream>>>(adj, adj_b, nullptr, hT, y_part, klen);
    else
        agg_kernel<64, 0><<<dim3(128, SPLITK), 256, 0, stream>>>(adj, nullptr, nullptr, hT, y_part, klen);

    head_kernel<SPLITK><<<2048, 256, 0, stream>>>(y_part, Wo0, bo0, Wo1, bo1, out);
}

// Round 2
// 172.175 us; speedup vs baseline: 1.3572x; 1.3572x over previous
//
#include <hip/hip_runtime.h>

#define N 8192

typedef __attribute__((ext_vector_type(8))) short short8;
typedef __attribute__((ext_vector_type(4))) float f32x4;

__device__ __forceinline__ unsigned short f2bf(float f) {
    union { float f; unsigned int u; } v; v.f = f;
    unsigned int r = v.u + 0x7FFFu + ((v.u >> 16) & 1u);  // round-to-nearest-even
    return (unsigned short)(r >> 16);
}

__device__ __forceinline__ void gl2lds16(const void* g, void* l) {
    __builtin_amdgcn_global_load_lds(
        (const __attribute__((address_space(1))) unsigned int*)g,
        (__attribute__((address_space(3))) unsigned int*)l, 16, 0, 0);
}

// ---------------------------------------------------------------------------
// Aggregation: y_partial[split] = adj[rows, ksplit] @ h
// MODE 0: adj f32 load (no writeback)  MODE 1: f32 load + pre-swizzled bf16
// writeback  MODE 2: linear global_load_lds of pre-swizzled bf16 adj.
// hT is stored PRE-SWIZZLED (col ^ ((c&7)<<3)) so staging is always linear.
// LDS tiles row-major bf16, fragment reads use byte ^ ((row&7)<<4).
// BM=64 rows, 4 waves, wave w -> rows [16w,16w+16), NC/16 col-tiles.
// ---------------------------------------------------------------------------
template<int NC, int BK, int MODE>
__global__ __launch_bounds__(256) void agg_kernel(
    const float* __restrict__ adj,
    const unsigned short* __restrict__ adj_b_in,
    unsigned short* __restrict__ adj_b_out,
    const unsigned short* __restrict__ hT,   // [NC][N] bf16, pre-swizzled
    float* __restrict__ y,                   // [S][N][NC] f32 partials
    int klen)
{
    constexpr int BM = 64;
    constexpr int NCT = NC / 16;
    constexpr int ROWB = BK * 2;             // bytes per LDS row
    __shared__ unsigned short as_[BM * BK];
    __shared__ unsigned short hs_[NC * BK];
    char* asb = (char*)as_;
    char* hsb = (char*)hs_;

    const int tid = threadIdx.x;
    const int w  = tid >> 6;
    const int l  = tid & 63;
    const int hi = l >> 4;
    const int lr = l & 15;
    const int row0 = blockIdx.x * BM;
    const int k00  = blockIdx.y * klen;
    const int nt   = klen / BK;

    f32x4 acc[NCT];
    #pragma unroll
    for (int i = 0; i < NCT; ++i) acc[i] = f32x4{0.f, 0.f, 0.f, 0.f};

    if (MODE == 2) {
        constexpr int TA = (BM * ROWB) / 1024;   // 1KB chunks, adj tile
        constexpr int TH = (NC * ROWB) / 1024;   // 1KB chunks, hT tile
        constexpr int GR = ROWB / 16;            // 16B granules per row
        constexpr int RPC = 1024 / ROWB;         // rows per chunk
        for (int t = 0; t < nt; ++t) {
            const int kb = k00 + t * BK;
            for (int i = w; i < TA; i += 4) {
                int r = i * RPC + l / GR;
                int g = l % GR;
                gl2lds16(adj_b_in + (size_t)(row0 + r) * N + kb + 8 * g,
                         asb + i * 1024);
            }
            for (int i = w; i < TH; i += 4) {
                int c = i * RPC + l / GR;
                int g = l % GR;
                gl2lds16(hT + (size_t)c * N + kb + 8 * g, hsb + i * 1024);
            }
            __syncthreads();
            #pragma unroll
            for (int kk = 0; kk < BK; kk += 32) {
                const int arow = 16 * w + lr;
                short8 a = *reinterpret_cast<const short8*>(
                    asb + arow * ROWB + ((2 * kk + 16 * hi) ^ ((arow & 7) << 4)));
                #pragma unroll
                for (int ct = 0; ct < NCT; ++ct) {
                    const int bcol = 16 * ct + lr;
                    short8 b = *reinterpret_cast<const short8*>(
                        hsb + bcol * ROWB + ((2 * kk + 16 * hi) ^ ((bcol & 7) << 4)));
                    acc[ct] = __builtin_amdgcn_mfma_f32_16x16x32_bf16(a, b, acc[ct], 0, 0, 0);
                }
            }
            __syncthreads();
        }
    } else {
        // MODE 0/1: requires BK==128. 8 float4 per thread, reg-prefetch pipeline.
        constexpr int LV = 8;
        constexpr int TH = (NC * ROWB) / 1024;
        float4 pf[LV];
        // prologue load tile 0
        #pragma unroll
        for (int it = 0; it < LV; ++it) {
            int idx = tid + it * 256, r = idx >> 5, q = idx & 31;
            pf[it] = *reinterpret_cast<const float4*>(
                adj + (size_t)(row0 + r) * N + k00 + 4 * q);
        }
        for (int t = 0; t < nt; ++t) {
            const int kb = k00 + t * BK;
            // STORE phase: convert + LDS write (swizzled) + global writeback
            #pragma unroll
            for (int it = 0; it < LV; ++it) {
                int idx = tid + it * 256, r = idx >> 5, q = idx & 31;
                ushort4 u;
                u.x = f2bf(pf[it].x); u.y = f2bf(pf[it].y);
                u.z = f2bf(pf[it].z); u.w = f2bf(pf[it].w);
                *reinterpret_cast<ushort4*>(
                    asb + r * ROWB + ((8 * q) ^ ((r & 7) << 4))) = u;
                if (MODE == 1)
                    *reinterpret_cast<ushort4*>(
                        adj_b_out + (size_t)(row0 + r) * N + kb +
                        ((4 * q) ^ ((r & 7) << 3))) = u;
            }
            // hT tile: linear gllds (content pre-swizzled)
            for (int i = w; i < TH; i += 4) {
                int c = i * 4 + l / 16;   // 4 rows per 1KB chunk (ROWB=256)
                int g = l % 16;
                gl2lds16(hT + (size_t)c * N + kb + 8 * g, hsb + i * 1024);
            }
            __syncthreads();
            // issue next tile's global loads (overlap with MFMA below)
            if (t + 1 < nt) {
                #pragma unroll
                for (int it = 0; it < LV; ++it) {
                    int idx = tid + it * 256, r = idx >> 5, q = idx & 31;
                    pf[it] = *reinterpret_cast<const float4*>(
                        adj + (size_t)(row0 + r) * N + kb + BK + 4 * q);
                }
            }
            #pragma unroll
            for (int kk = 0; kk < BK; kk += 32) {
                const int arow = 16 * w + lr;
                short8 a = *reinterpret_cast<const short8*>(
                    asb + arow * ROWB + ((2 * kk + 16 * hi) ^ ((arow & 7) << 4)));
                #pragma unroll
                for (int ct = 0; ct < NCT; ++ct) {
                    const int bcol = 16 * ct + lr;
                    short8 b = *reinterpret_cast<const short8*>(
                        hsb + bcol * ROWB + ((2 * kk + 16 * hi) ^ ((bcol & 7) << 4)));
                    acc[ct] = __builtin_amdgcn_mfma_f32_16x16x32_bf16(a, b, acc[ct], 0, 0, 0);
                }
            }
            __syncthreads();
        }
    }
    // write partials: D layout col=lane&15, row=4*(lane>>4)+reg
    float* yp = y + (size_t)blockIdx.y * N * NC;
    #pragma unroll
    for (int ct = 0; ct < NCT; ++ct) {
        #pragma unroll
        for (int r = 0; r < 4; ++r) {
            yp[(size_t)(row0 + 16 * w + 4 * hi + r) * NC + 16 * ct + lr] = acc[ct][r];
        }
    }
}

// ---------------------------------------------------------------------------
// lin0: hT = bf16((x @ W0 + b0)^T), pre-swizzled columns
// ---------------------------------------------------------------------------
__global__ __launch_bounds__(256) void lin0_kernel(
    const float* __restrict__ x, const float* __restrict__ W,
    const float* __restrict__ b, unsigned short* __restrict__ hT)
{
    __shared__ float xs[64][129];
    const int tid = threadIdx.x;
    const int row0 = blockIdx.x * 64;
    #pragma unroll
    for (int it = 0; it < 8; ++it) {
        int idx = tid + it * 256;
        int r = idx >> 5, q = idx & 31;
        float4 v = *reinterpret_cast<const float4*>(x + (size_t)(row0 + r) * 128 + 4 * q);
        xs[r][4 * q + 0] = v.x; xs[r][4 * q + 1] = v.y;
        xs[r][4 * q + 2] = v.z; xs[r][4 * q + 3] = v.w;
    }
    __syncthreads();
    const int w = tid >> 6, l = tid & 63;
    float acc[4] = {b[w], b[w + 4], b[w + 8], b[w + 12]};
    for (int k = 0; k < 128; ++k) {
        float xv = xs[l][k];
        #pragma unroll
        for (int cc = 0; cc < 4; ++cc) acc[cc] += xv * W[k * 16 + w + 4 * cc];
    }
    #pragma unroll
    for (int cc = 0; cc < 4; ++cc) {
        int c = w + 4 * cc;
        hT[(size_t)c * N + ((row0 + l) ^ ((c & 7) << 3))] = f2bf(acc[cc]);
    }
}

// ---------------------------------------------------------------------------
// mid linear: hT = bf16((relu(sum_s y_s) @ W + b)^T), pre-swizzled columns
// ---------------------------------------------------------------------------
template<int NIN, int NOUT, int S>
__global__ __launch_bounds__(256) void mid_linear_kernel(
    const float* __restrict__ y,     // [S][N][NIN]
    const float* __restrict__ W,     // [NIN][NOUT]
    const float* __restrict__ b,
    unsigned short* __restrict__ hT) // [NOUT][N]
{
    __shared__ float xs[64][NIN + 1];
    const int tid = threadIdx.x;
    const int row0 = blockIdx.x * 64;
    constexpr int NF4 = 64 * NIN / 4;
    #pragma unroll
    for (int idx0 = 0; idx0 < NF4; idx0 += 256) {
        int idx = idx0 + tid;
        int r = idx / (NIN / 4), q = idx % (NIN / 4);
        size_t off = (size_t)(row0 + r) * NIN + 4 * q;
        float4 v = *reinterpret_cast<const float4*>(y + off);
        #pragma unroll
        for (int s = 1; s < S; ++s) {
            float4 t = *reinterpret_cast<const float4*>(y + (size_t)s * N * NIN + off);
            v.x += t.x; v.y += t.y; v.z += t.z; v.w += t.w;
        }
        xs[r][4 * q + 0] = fmaxf(v.x, 0.f);
        xs[r][4 * q + 1] = fmaxf(v.y, 0.f);
        xs[r][4 * q + 2] = fmaxf(v.z, 0.f);
        xs[r][4 * q + 3] = fmaxf(v.w, 0.f);
    }
    __syncthreads();
    const int w = tid >> 6, l = tid & 63;
    constexpr int CC = NOUT / 4;
    float acc[CC];
    #pragma unroll
    for (int cc = 0; cc < CC; ++cc) acc[cc] = b[w + 4 * cc];
    for (int k = 0; k < NIN; ++k) {
        float xv = xs[l][k];
        #pragma unroll
        for (int cc = 0; cc < CC; ++cc) acc[cc] += xv * W[k * NOUT + w + 4 * cc];
    }
    #pragma unroll
    for (int cc = 0; cc < CC; ++cc) {
        int c = w + 4 * cc;
        hT[(size_t)c * N + ((row0 + l) ^ ((c & 7) << 3))] = f2bf(acc[cc]);
    }
}

// ---------------------------------------------------------------------------
// head: out = relu(relu(sum_s y_s) @ Wo0 + bo0) @ Wo1 + bo1
// ---------------------------------------------------------------------------
template<int S>
__global__ __launch_bounds__(256) void head_kernel(
    const float* __restrict__ y,   // [S][N][64]
    const float* __restrict__ Wo0, const float* __restrict__ bo0,
    const float* __restrict__ Wo1, const float* __restrict__ bo1,
    float* __restrict__ out)
{
    __shared__ float xr[4][64];
    __shared__ float hid[4][32];
    const int tid = threadIdx.x;
    const int row0 = blockIdx.x * 4;
    {
        int r = tid >> 6, k = tid & 63;
        size_t off = (size_t)(row0 + r) * 64 + k;
        float v = y[off];
        #pragma unroll
        for (int s = 1; s < S; ++s) v += y[(size_t)s * N * 64 + off];
        xr[r][k] = fmaxf(v, 0.f);
    }
    __syncthreads();
    const int w = tid >> 6, l = tid & 63;
    if (l < 32) {
        float acc = bo0[l];
        #pragma unroll
        for (int k = 0; k < 64; ++k) acc += xr[w][k] * Wo0[k * 32 + l];
        hid[w][l] = fmaxf(acc, 0.f);
    }
    __syncthreads();
    if (l < 10) {
        float acc = bo1[l];
        #pragma unroll
        for (int k = 0; k < 32; ++k) acc += hid[w][k] * Wo1[k * 10 + l];
        out[(size_t)(row0 + w) * 10 + l] = acc;
    }
}

extern "C" void kernel_launch(void* const* d_in, const int* in_sizes, int n_in,
                              void* d_out, int out_size, void* d_ws, size_t ws_size,
                              hipStream_t stream) {
    const float* x   = (const float*)d_in[0];
    const float* adj = (const float*)d_in[1];
    const float* W0  = (const float*)d_in[2];
    const float* b0  = (const float*)d_in[3];
    const float* W1  = (const float*)d_in[4];
    const float* b1  = (const float*)d_in[5];
    const float* W2  = (const float*)d_in[6];
    const float* b2  = (const float*)d_in[7];
    const float* Wo0 = (const float*)d_in[8];
    const float* bo0 = (const float*)d_in[9];
    const float* Wo1 = (const float*)d_in[10];
    const float* bo1 = (const float*)d_in[11];
    float* out = (float*)d_out;

    char* ws = (char*)d_ws;
    constexpr int S1 = 16, S2 = 8, S3 = 8;
    float* y_part          = (float*)ws;                          // <= 16 MiB
    unsigned short* hT     = (unsigned short*)(ws + (16u << 20)); // 1 MiB
    unsigned short* adj_b  = (unsigned short*)(ws + (24u << 20)); // 128 MiB
    const size_t NEED_FULL = ((size_t)24 << 20) + (size_t)N * N * 2;
    const bool cache = ws_size >= NEED_FULL;

    lin0_kernel<<<128, 256, 0, stream>>>(x, W0, b0, hT);

    if (cache)
        agg_kernel<16, 128, 1><<<dim3(128, S1), 256, 0, stream>>>(adj, nullptr, adj_b, hT, y_part, N / S1);
    else
        agg_kernel<16, 128, 0><<<dim3(128, S1), 256, 0, stream>>>(adj, nullptr, nullptr, hT, y_part, N / S1);

    mid_linear_kernel<16, 32, S1><<<128, 256, 0, stream>>>(y_part, W1, b1, hT);

    if (cache)
        agg_kernel<32, 128, 2><<<dim3(128, S2), 256, 0, stream>>>(adj, adj_b, nullptr, hT, y_part, N / S2);
    else
        agg_kernel<32, 128, 0><<<dim3(128, S2), 256, 0, stream>>>(adj, nullptr, nullptr, hT, y_part, N / S2);

    mid_linear_kernel<32, 64, S2><<<128, 256, 0, stream>>>(y_part, W2, b2, hT);

    if (cache)
        agg_kernel<64, 64, 2><<<dim3(128, S3), 256, 0, stream>>>(adj, adj_b, nullptr, hT, y_part, N / S3);
    else
        agg_kernel<64, 128, 0><<<dim3(128, S3), 256, 0, stream>>>(adj, nullptr, nullptr, hT, y_part, N / S3);

    head_kernel<S3><<<2048, 256, 0, stream>>>(y_part, Wo0, bo0, Wo1, bo1, out);
}